// Round 2
// baseline (397.611 us; speedup 1.0000x reference)
//
#include <hip/hip_runtime.h>

// Dempster-Schafer combine of two Dirichlet parameter maps.
//
// Algebraic simplification of the reference:
//   e1 = a1-1, e2 = a2-1, S = sum_c(alpha), u = C/S, b = e/S
//   out = b_a*S_a + 1, with S_a = C*denom/(u1*u2) and
//   b_a = (b1*b2 + b1*u2 + b2*u1)/denom
//   => denom cancels; C*b1*b2/(u1*u2) = e1*e2/C; C*b1*u2/(u1*u2) = e1; etc.
//   => out = e1*e2/C + e1 + e2 + 1 = (a1-1)*(a2-1)/C + a1 + a2 - 1
// Purely elementwise -> memory-bound streaming kernel.

__global__ __launch_bounds__(256) void ds_combine_kernel(
    const float4* __restrict__ a1,
    const float4* __restrict__ a2,
    float4* __restrict__ out,
    int n4) {
    constexpr float inv_c = 1.0f / 21.0f;
    const int stride = gridDim.x * blockDim.x;
    for (int i = blockIdx.x * blockDim.x + threadIdx.x; i < n4; i += stride) {
        const float4 x = a1[i];
        const float4 y = a2[i];
        float4 r;
        r.x = fmaf((x.x - 1.0f) * (y.x - 1.0f), inv_c, x.x + y.x - 1.0f);
        r.y = fmaf((x.y - 1.0f) * (y.y - 1.0f), inv_c, x.y + y.y - 1.0f);
        r.z = fmaf((x.z - 1.0f) * (y.z - 1.0f), inv_c, x.z + y.z - 1.0f);
        r.w = fmaf((x.w - 1.0f) * (y.w - 1.0f), inv_c, x.w + y.w - 1.0f);
        out[i] = r;
    }
}

extern "C" void kernel_launch(void* const* d_in, const int* in_sizes, int n_in,
                              void* d_out, int out_size, void* d_ws, size_t ws_size,
                              hipStream_t stream) {
    const float* a1 = (const float*)d_in[0];
    const float* a2 = (const float*)d_in[1];
    float* out = (float*)d_out;

    const int n = in_sizes[0];       // 8*21*512*512 = 44,040,192 (divisible by 4)
    const int n4 = n / 4;

    const int block = 256;
    // Memory-bound streaming: cap grid at 8 blocks/CU * 256 CU and grid-stride.
    int grid = (n4 + block - 1) / block;
    if (grid > 2048) grid = 2048;

    ds_combine_kernel<<<grid, block, 0, stream>>>(
        (const float4*)a1, (const float4*)a2, (float4*)out, n4);
}